// Round 2
// baseline (2796.324 us; speedup 1.0000x reference)
//
#include <hip/hip_runtime.h>
#include <cstdint>
#include <cstddef>

// ---------------------------------------------------------------------------
// Zeoformer forward. fp32 GEMMs + tabulated edge embedding.
// N=20000 nodes, E=320000 edges, B=64 graphs, F=256, CG=92, NL=4, NP=3.
// Edge embedding e_i(edge) depends only on scalar d=-1/||edge_attr||:
//   d -> RBF(256) -> ef = silu(@ee_W.T+b) -> e_i = ef@We_i.T+be_i
// so we tabulate e_i(d) on a T=4096 grid over [-8,0] and lerp per edge.
// RBF is exactly 0 (fp32) for d < -8, so clamping is exact there.
// ---------------------------------------------------------------------------

#define DEVFN static __device__ __forceinline__

DEVFN float siluf(float x) { return x / (1.f + expf(-x)); }

// ------------------------- generic GEMM: C = act(A @ W^T + bias) (+ res) ----
// A: [M,K] row-major (lda), W: [OUT,K] row-major, C: [M,OUT] (ldc)
template <int BM, int BN, int TM, int TN, int ACT>
__launch_bounds__(256) __global__
void gemm_nt(const float* __restrict__ A, int lda,
             const float* __restrict__ W,
             const float* __restrict__ bias,
             const float* __restrict__ res, int ldr,
             float* __restrict__ C, int ldc,
             int M, int K, int OUT)
{
    constexpr int BK = 16;
    __shared__ alignas(16) float As[BK][BM];
    __shared__ alignas(16) float Bs[BK][BN];
    const int tid = threadIdx.x;
    const int bm = blockIdx.x * BM;
    const int bn = blockIdx.y * BN;
    const int tr = (tid >> 4) * TM;
    const int tc = (tid & 15) * TN;

    float acc[TM][TN];
#pragma unroll
    for (int i = 0; i < TM; ++i)
#pragma unroll
        for (int j = 0; j < TN; ++j) acc[i][j] = 0.f;

    for (int k0 = 0; k0 < K; k0 += BK) {
#pragma unroll
        for (int it = 0; it < BM / 64; ++it) {
            int idx = tid + it * 256;
            int m = idx >> 2, kq = idx & 3;
            int gm = bm + m, gk = k0 + kq * 4;
            float t[4] = {0.f, 0.f, 0.f, 0.f};
            if (gm < M) {
                if (gk + 3 < K) {
                    float4 v4 = *reinterpret_cast<const float4*>(A + (size_t)gm * lda + gk);
                    t[0] = v4.x; t[1] = v4.y; t[2] = v4.z; t[3] = v4.w;
                } else {
#pragma unroll
                    for (int j = 0; j < 4; ++j)
                        if (gk + j < K) t[j] = A[(size_t)gm * lda + gk + j];
                }
            }
            As[kq * 4 + 0][m] = t[0];
            As[kq * 4 + 1][m] = t[1];
            As[kq * 4 + 2][m] = t[2];
            As[kq * 4 + 3][m] = t[3];
        }
#pragma unroll
        for (int it = 0; it < BN / 64; ++it) {
            int idx = tid + it * 256;
            int o = idx >> 2, kq = idx & 3;
            int go = bn + o, gk = k0 + kq * 4;
            float t[4] = {0.f, 0.f, 0.f, 0.f};
            if (go < OUT) {
                if (gk + 3 < K) {
                    float4 v4 = *reinterpret_cast<const float4*>(W + (size_t)go * K + gk);
                    t[0] = v4.x; t[1] = v4.y; t[2] = v4.z; t[3] = v4.w;
                } else {
#pragma unroll
                    for (int j = 0; j < 4; ++j)
                        if (gk + j < K) t[j] = W[(size_t)go * K + gk + j];
                }
            }
            Bs[kq * 4 + 0][o] = t[0];
            Bs[kq * 4 + 1][o] = t[1];
            Bs[kq * 4 + 2][o] = t[2];
            Bs[kq * 4 + 3][o] = t[3];
        }
        __syncthreads();
#pragma unroll
        for (int kk = 0; kk < BK; ++kk) {
            float a[TM], b[TN];
#pragma unroll
            for (int p = 0; p < TM; p += 4) {
                float4 v4 = *reinterpret_cast<const float4*>(&As[kk][tr + p]);
                a[p] = v4.x; a[p + 1] = v4.y; a[p + 2] = v4.z; a[p + 3] = v4.w;
            }
#pragma unroll
            for (int p = 0; p < TN; p += 4) {
                float4 v4 = *reinterpret_cast<const float4*>(&Bs[kk][tc + p]);
                b[p] = v4.x; b[p + 1] = v4.y; b[p + 2] = v4.z; b[p + 3] = v4.w;
            }
#pragma unroll
            for (int i = 0; i < TM; ++i)
#pragma unroll
                for (int j = 0; j < TN; ++j) acc[i][j] += a[i] * b[j];
        }
        __syncthreads();
    }

#pragma unroll
    for (int i = 0; i < TM; ++i) {
        int m = bm + tr + i;
        if (m >= M) continue;
#pragma unroll
        for (int j = 0; j < TN; ++j) {
            int o = bn + tc + j;
            if (o >= OUT) continue;
            float v = acc[i][j];
            if (bias) v += bias[o];
            if (ACT == 1) v = siluf(v);
            if (res) v += res[(size_t)m * ldr + o];
            C[(size_t)m * ldc + o] = v;
        }
    }
}

// ------------------------- small elementwise kernels ------------------------
__global__ void node_prep_k(const float* __restrict__ x, float* __restrict__ fx,
                            float* __restrict__ px, int n)
{
    int i = blockIdx.x * blockDim.x + threadIdx.x;
    if (i < n) {
        float v = x[i];
        fx[i] = floorf(v);
        px[i] = (v - truncf(v)) * 1000.f;
    }
}

// RBF table over d-grid: out[t][j] = exp(-42.5*(d_t - c_j)^2)
__global__ void table_rbf_k(float* __restrict__ out, int T, float dmin, float step)
{
    int idx = blockIdx.x * blockDim.x + threadIdx.x;   // T*64 threads
    if (idx >= T * 64) return;
    int t = idx >> 6, j4 = (idx & 63) * 4;
    float dv = dmin + step * (float)t;
    float r[4];
#pragma unroll
    for (int j = 0; j < 4; ++j) {
        float c = -6.f + 6.f * (float)(j4 + j) * (1.f / 255.f);
        float u = dv - c;
        r[j] = expf(-42.5f * u * u);
    }
    float4 v = {r[0], r[1], r[2], r[3]};
    *reinterpret_cast<float4*>(out + (size_t)t * 256 + j4) = v;
}

// per-edge: d = -1/||ea||, table coord (i0, fr)
__global__ void edge_prep_k(const float* __restrict__ ea, int* __restrict__ i0,
                            float* __restrict__ fr, int E, float dmin, float invstep, int T)
{
    int i = blockIdx.x * blockDim.x + threadIdx.x;
    if (i < E) {
        float a = ea[(size_t)i * 3], b = ea[(size_t)i * 3 + 1], c = ea[(size_t)i * 3 + 2];
        float d = -1.f / sqrtf(a * a + b * b + c * c);   // < 0, may be -inf
        float u = (d - dmin) * invstep;
        u = fminf(fmaxf(u, 0.f), (float)(T - 1) - 1e-3f);
        int t0 = (int)u;
        i0[i] = t0;
        fr[i] = u - (float)t0;
    }
}

__global__ void ppe_prep_k(float* __restrict__ ppe, const float* __restrict__ h,
                           const float* __restrict__ pg, const float* __restrict__ pbeta,
                           float* __restrict__ bn, int n)
{
    int i = blockIdx.x * blockDim.x + threadIdx.x;
    if (i < n) {
        float adj = ppe[i] + h[i];
        ppe[i] = adj;
        int f = i & 255;
        bn[i] = adj * pg[f] + pbeta[f];
    }
}

__global__ void gate_k(const float* __restrict__ x1, const float* __restrict__ a2,
                       float* __restrict__ g, int n)
{
    int i = blockIdx.x * blockDim.x + threadIdx.x;
    if (i < n) {
        int m = i >> 8, f = i & 255;
        float x2 = a2[(size_t)m * 512 + 256 + f];
        float ge = 0.5f * x2 * (1.f + erff(x2 * 0.70710678118654752f));
        g[i] = x1[i] * ge;
    }
}

// ------------------------- edge sort by dst (counting sort) ----------------
__global__ void hist_k(const int* __restrict__ dst, int* __restrict__ deg, int E)
{
    int i = blockIdx.x * blockDim.x + threadIdx.x;
    if (i < E) atomicAdd(&deg[dst[i]], 1);
}

__global__ void scan_k(const int* __restrict__ deg, int* __restrict__ off, int n)
{
    __shared__ int buf[1024];
    __shared__ int carry;
    const int t = threadIdx.x;
    if (t == 0) carry = 0;
    __syncthreads();
    for (int base = 0; base < n; base += 1024) {
        int i = base + t;
        int v = (i < n) ? deg[i] : 0;
        buf[t] = v;
        __syncthreads();
        for (int s = 1; s < 1024; s <<= 1) {
            int add = (t >= s) ? buf[t - s] : 0;
            __syncthreads();
            buf[t] += add;
            __syncthreads();
        }
        if (i < n) off[i] = carry + buf[t] - v;
        __syncthreads();
        if (t == 0) carry += buf[1023];
        __syncthreads();
    }
    if (t == 0) off[n] = carry;
}

__global__ void copy_int_k(const int* __restrict__ a, int* __restrict__ b, int n)
{
    int i = blockIdx.x * blockDim.x + threadIdx.x;
    if (i < n) b[i] = a[i];
}

__global__ void scatter_k(const int* __restrict__ dst, int* __restrict__ cursor,
                          int* __restrict__ esort, int E)
{
    int i = blockIdx.x * blockDim.x + threadIdx.x;
    if (i < E) {
        int p = atomicAdd(&cursor[dst[i]], 1);
        esort[p] = i;
    }
}

// ------------------------- attention aggregate (wave per node) --------------
// hn[n] += softmax_over_incoming( q[n]·(k[src]+e)/16 ) weighted (v[src]+e)
// e per edge lerped from etab [T,256] at (i0, fr).
__launch_bounds__(256) __global__
void attn_agg_k(const float* __restrict__ q, const float* __restrict__ kx,
                const float* __restrict__ vx, const float* __restrict__ etab,
                const int* __restrict__ ei0, const float* __restrict__ efr,
                const int* __restrict__ src, const int* __restrict__ esort,
                const int* __restrict__ off, float* __restrict__ sbuf,
                float* __restrict__ hn, int Nn)
{
    int node = blockIdx.x * 4 + (threadIdx.x >> 6);
    if (node >= Nn) return;
    int lane = threadIdx.x & 63;
    int lo = off[node], hi = off[node + 1];
    if (lo >= hi) return;   // isolated node: agg contribution is 0

    float4 qv = *reinterpret_cast<const float4*>(q + (size_t)node * 256 + lane * 4);

    // pass 1: raw dot per edge -> sbuf[jj]; track max (scale 1/16 is monotone)
    float mx = -3.4e38f;
    for (int jj = lo; jj < hi; ++jj) {
        int eid = esort[jj];
        int sp = src[eid];
        int t0 = ei0[eid];
        float f = efr[eid];
        float4 kv = *reinterpret_cast<const float4*>(kx + (size_t)sp * 256 + lane * 4);
        float4 e0 = *reinterpret_cast<const float4*>(etab + (size_t)t0 * 256 + lane * 4);
        float4 e1 = *reinterpret_cast<const float4*>(etab + (size_t)(t0 + 1) * 256 + lane * 4);
        float ex0 = e0.x + f * (e1.x - e0.x);
        float ex1 = e0.y + f * (e1.y - e0.y);
        float ex2 = e0.z + f * (e1.z - e0.z);
        float ex3 = e0.w + f * (e1.w - e0.w);
        float p = qv.x * (kv.x + ex0) + qv.y * (kv.y + ex1) +
                  qv.z * (kv.z + ex2) + qv.w * (kv.w + ex3);
#pragma unroll
        for (int s = 32; s; s >>= 1) p += __shfl_xor(p, s, 64);
        if (lane == 0) sbuf[jj] = p;
        mx = fmaxf(mx, p);
    }
    // pass 2: w = exp((dot-mx)/16), accumulate w*(v[src]+e)
    float ax = 0.f, ay = 0.f, az = 0.f, aw = 0.f, den = 0.f;
    for (int jj = lo; jj < hi; ++jj) {
        int eid = esort[jj];
        int sp = src[eid];
        int t0 = ei0[eid];
        float f = efr[eid];
        float4 vv = *reinterpret_cast<const float4*>(vx + (size_t)sp * 256 + lane * 4);
        float4 e0 = *reinterpret_cast<const float4*>(etab + (size_t)t0 * 256 + lane * 4);
        float4 e1 = *reinterpret_cast<const float4*>(etab + (size_t)(t0 + 1) * 256 + lane * 4);
        float ex0 = e0.x + f * (e1.x - e0.x);
        float ex1 = e0.y + f * (e1.y - e0.y);
        float ex2 = e0.z + f * (e1.z - e0.z);
        float ex3 = e0.w + f * (e1.w - e0.w);
        float w = expf((sbuf[jj] - mx) * 0.0625f);
        den += w;
        ax += w * (vv.x + ex0);
        ay += w * (vv.y + ex1);
        az += w * (vv.z + ex2);
        aw += w * (vv.w + ex3);
    }
    float inv = 1.f / den;
    float4* o4 = reinterpret_cast<float4*>(hn + (size_t)node * 256 + lane * 4);
    float4 cur = *o4;
    cur.x += ax * inv; cur.y += ay * inv; cur.z += az * inv; cur.w += aw * inv;
    *o4 = cur;
}

// ------------------------- pooling / output ---------------------------------
__launch_bounds__(256) __global__
void pool_mean_k(const float* __restrict__ h, const int* __restrict__ batch,
                 float* __restrict__ tot, int Nn)
{
    int g = blockIdx.x;
    __shared__ int sl, sh;
    if (threadIdx.x == 0) {
        int lo = 0, hi = Nn;
        while (lo < hi) { int mid = (lo + hi) >> 1; if (batch[mid] < g) lo = mid + 1; else hi = mid; }
        sl = lo;
        lo = 0; hi = Nn;
        while (lo < hi) { int mid = (lo + hi) >> 1; if (batch[mid] < g + 1) lo = mid + 1; else hi = mid; }
        sh = lo;
    }
    __syncthreads();
    float acc = 0.f;
    for (int n = sl; n < sh; ++n) acc += h[(size_t)n * 256 + threadIdx.x];
    float c = (float)(sh - sl);
    if (c < 1.f) c = 1.f;
    tot[(size_t)g * 256 + threadIdx.x] = acc / c;
}

__launch_bounds__(256) __global__
void out_k(const float* __restrict__ crystal, const float* __restrict__ oW,
           const float* __restrict__ ob, const float* __restrict__ nosda,
           float* __restrict__ out, int Bn)
{
    int b = blockIdx.x;
    __shared__ float red[256];
    float p = crystal[(size_t)b * 256 + threadIdx.x] * oW[threadIdx.x];
    red[threadIdx.x] = p;
    __syncthreads();
    for (int s = 128; s; s >>= 1) {
        if (threadIdx.x < s) red[threadIdx.x] += red[threadIdx.x + s];
        __syncthreads();
    }
    if (threadIdx.x == 0) out[b] = (red[0] + ob[0]) / nosda[b];
}

// ---------------------------------------------------------------------------
extern "C" void kernel_launch(void* const* d_in, const int* in_sizes, int n_in,
                              void* d_out, int out_size, void* d_ws, size_t ws_size,
                              hipStream_t stream)
{
    const float* x     = (const float*)d_in[0];
    const int*   ei    = (const int*)d_in[1];
    const float* ea    = (const float*)d_in[2];
    const int*   batch = (const int*)d_in[3];
    const float* nosda = (const float*)d_in[4];
    const float* ae_W1 = (const float*)d_in[5];
    const float* ae_b1 = (const float*)d_in[6];
    const float* ae_W2 = (const float*)d_in[7];
    const float* ae_b2 = (const float*)d_in[8];
    const float* ee_W  = (const float*)d_in[9];
    const float* ee_b  = (const float*)d_in[10];
    const float* pe_W  = (const float*)d_in[11];
    const float* pe_b  = (const float*)d_in[12];
    const float* Wq    = (const float*)d_in[13];
    const float* bq    = (const float*)d_in[14];
    const float* Wk    = (const float*)d_in[15];
    const float* bk    = (const float*)d_in[16];
    const float* Wv    = (const float*)d_in[17];
    const float* bv    = (const float*)d_in[18];
    const float* We    = (const float*)d_in[19];
    const float* be    = (const float*)d_in[20];
    const float* Ws    = (const float*)d_in[21];
    const float* bs    = (const float*)d_in[22];
    const float* pW1   = (const float*)d_in[23];
    const float* pb1   = (const float*)d_in[24];
    const float* pW2   = (const float*)d_in[25];
    const float* pb2   = (const float*)d_in[26];
    const float* pW3   = (const float*)d_in[27];
    const float* pb3   = (const float*)d_in[28];
    const float* pg    = (const float*)d_in[29];
    const float* pbeta = (const float*)d_in[30];
    const float* fc_W  = (const float*)d_in[31];
    const float* fc_b  = (const float*)d_in[32];
    const float* out_W = (const float*)d_in[33];
    const float* out_b = (const float*)d_in[34];

    const int CG = 92, F = 256;
    const int N = in_sizes[0] / CG;
    const int E = in_sizes[1] / 2;
    const int B = in_sizes[4];
    const int T = 4096;                       // e-table resolution
    const float DMIN = -8.f, DMAX = 0.f;
    const float STEP = (DMAX - DMIN) / (float)(T - 1);
    const int* src  = ei;
    const int* dstp = ei + E;

    // ---- workspace carve-up (~210 MB) -------------------------------------
    float* w = (float*)d_ws;
    auto take = [&](size_t n) { float* p = w; w += n; return p; };
    const size_t NF = (size_t)N * F;
    float* hb0  = take(NF);
    float* hb1  = take(NF);
    float* ppeb = take(NF);
    float* qb   = take(NF);
    float* kb   = take(NF);
    float* vb   = take(NF);
    float* a2b  = take(2 * NF);
    float* fx   = take((size_t)N * CG);
    float* px   = take((size_t)N * CG);
    float* rbft = take((size_t)T * F);        // RBF table [T,256]
    float* eft  = take((size_t)T * F);        // ef table  [T,256]
    float* etab = take((size_t)4 * T * F);    // e tables, 4 layers [4,T,256]
    float* efr  = take(E);                    // lerp fraction per edge
    float* sbuf = take(E);                    // raw dot per sorted edge slot
    float* totb = take((size_t)B * F);
    float* cryb = take((size_t)B * F);
    int* ei0    = (int*)w; w += E;            // table index per edge
    int* deg    = (int*)w; w += N;
    int* offb   = (int*)w; w += (N + 1);
    int* curb   = (int*)w; w += N;
    int* esort  = (int*)w; w += E;
    size_t need = (size_t)((char*)w - (char*)d_ws);
    if (need > ws_size) return;               // fail loud (wrong answer), not a fault
    (void)n_in; (void)out_size;

    dim3 blk(256);
    auto g1 = [](int n) { return dim3((n + 255) / 256); };

    auto gemm128 = [&](const float* A, int lda, const float* Wt, const float* bias,
                       const float* res, int ldr, float* C, int ldc,
                       int M, int K, int OUT, int act) {
        dim3 grid((M + 127) / 128, (OUT + 127) / 128);
        if (act)
            gemm_nt<128, 128, 8, 8, 1><<<grid, blk, 0, stream>>>(A, lda, Wt, bias, res, ldr, C, ldc, M, K, OUT);
        else
            gemm_nt<128, 128, 8, 8, 0><<<grid, blk, 0, stream>>>(A, lda, Wt, bias, res, ldr, C, ldc, M, K, OUT);
    };
    auto gemm64 = [&](const float* A, int lda, const float* Wt, const float* bias,
                      const float* res, int ldr, float* C, int ldc,
                      int M, int K, int OUT, int act) {
        dim3 grid((M + 63) / 64, (OUT + 63) / 64);
        if (act)
            gemm_nt<64, 64, 4, 4, 1><<<grid, blk, 0, stream>>>(A, lda, Wt, bias, res, ldr, C, ldc, M, K, OUT);
        else
            gemm_nt<64, 64, 4, 4, 0><<<grid, blk, 0, stream>>>(A, lda, Wt, bias, res, ldr, C, ldc, M, K, OUT);
    };

    // ---- prep + tables
    node_prep_k<<<g1(N * CG), blk, 0, stream>>>(x, fx, px, N * CG);
    edge_prep_k<<<g1(E), blk, 0, stream>>>(ea, ei0, efr, E, DMIN, 1.f / STEP, T);
    table_rbf_k<<<g1(T * 64), blk, 0, stream>>>(rbft, T, DMIN, STEP);

    // ef table = silu(rbf @ ee_W.T + ee_b)   [T,256]
    gemm128(rbft, F, ee_W, ee_b, nullptr, 0, eft, F, T, F, F, 1);
    // per-layer e tables: e_i = ef @ We_i.T + be_i
    for (int i = 0; i < 4; ++i)
        gemm128(eft, F, We + (size_t)i * F * F, be + (size_t)i * F, nullptr, 0,
                etab + (size_t)i * T * F, F, T, F, F, 0);

    // ---- embeddings
    gemm64(fx, CG, ae_W1, ae_b1, nullptr, 0, kb, F, N, CG, F, 1);   // t1 = silu(...)
    gemm64(kb, F, ae_W2, ae_b2, nullptr, 0, hb0, F, N, F, F, 0);    // h
    gemm64(px, CG, pe_W, pe_b, nullptr, 0, ppeb, F, N, CG, F, 0);   // ppe

    // ---- counting-sort edges by dst (reused by all 4 conv layers)
    hipMemsetAsync(deg, 0, (size_t)N * sizeof(int), stream);
    hist_k<<<g1(E), blk, 0, stream>>>(dstp, deg, E);
    scan_k<<<1, 1024, 0, stream>>>(deg, offb, N);
    copy_int_k<<<g1(N), blk, 0, stream>>>(offb, curb, N);
    scatter_k<<<g1(E), blk, 0, stream>>>(dstp, curb, esort, E);

    float* h  = hb0;
    float* hn = hb1;
    for (int i = 0; i < 4; ++i) {
        const float* Wq_i = Wq + (size_t)i * F * F; const float* bq_i = bq + (size_t)i * F;
        const float* Wk_i = Wk + (size_t)i * F * F; const float* bk_i = bk + (size_t)i * F;
        const float* Wv_i = Wv + (size_t)i * F * F; const float* bv_i = bv + (size_t)i * F;
        const float* Ws_i = Ws + (size_t)i * F * F; const float* bs_i = bs + (size_t)i * F;

        gemm64(h, F, Wq_i, bq_i, nullptr, 0, qb, F, N, F, F, 0);
        gemm64(h, F, Wk_i, bk_i, nullptr, 0, kb, F, N, F, F, 0);
        gemm64(h, F, Wv_i, bv_i, nullptr, 0, vb, F, N, F, F, 0);
        gemm64(h, F, Ws_i, bs_i, nullptr, 0, hn, F, N, F, F, 0);    // skip path

        attn_agg_k<<<dim3((N + 3) / 4), blk, 0, stream>>>(
            qb, kb, vb, etab + (size_t)i * T * F, ei0, efr, src, esort, offb, sbuf, hn, N);
        { float* t = h; h = hn; hn = t; }

        if (i < 3) {
            const float* pW1_i = pW1 + (size_t)i * 2 * F * F; const float* pb1_i = pb1 + (size_t)i * 2 * F;
            const float* pW2_i = pW2 + (size_t)i * F * F;     const float* pb2_i = pb2 + (size_t)i * F;
            const float* pW3_i = pW3 + (size_t)i * F * F;     const float* pb3_i = pb3 + (size_t)i * F;

            ppe_prep_k<<<g1(N * F), blk, 0, stream>>>(ppeb, h, pg + (size_t)i * F, pbeta + (size_t)i * F, vb, N * F);
            gemm64(vb, F, pW1_i, pb1_i, nullptr, 0, a2b, 2 * F, N, F, 2 * F, 0);   // a2 [N,512]
            gemm64(a2b, 2 * F, pW2_i, pb2_i, nullptr, 0, qb, F, N, F, F, 0);       // x1
            gate_k<<<g1(N * F), blk, 0, stream>>>(qb, a2b, kb, N * F);             // g = x1*gelu(x2)
            gemm64(kb, F, pW3_i, pb3_i, h, F, hn, F, N, F, F, 0);                  // h' = g@pW3.T+pb3 + h
            { float* t = h; h = hn; hn = t; }
        }
    }

    // ---- pooling + head
    pool_mean_k<<<dim3(B), blk, 0, stream>>>(h, batch, totb, N);
    gemm64(totb, F, fc_W, fc_b, totb, F, cryb, F, B, F, F, 1);       // crystal = tot + silu(...)
    out_k<<<dim3(B), blk, 0, stream>>>(cryb, out_W, out_b, nosda, (float*)d_out, B);
}

// Round 6
// 2256.747 us; speedup vs baseline: 1.2391x; 1.2391x over previous
//
#include <hip/hip_runtime.h>
#include <cstdint>
#include <cstddef>

// ---------------------------------------------------------------------------
// Zeoformer forward. Split-bf16 (hi+lo, 3-product) MFMA GEMMs ~= fp32
// precision at MFMA speed + tabulated edge embedding + fp32 attention.
// N=20000, E=320000, B=64, F=256, CG=92, NL=4, NP=3.
// (Resubmission: round-5 bench was a broker timeout; kernel never ran.)
// Round-4 failed on precision only (absmax 0.5 vs thr 0.345, ~1e-3 rel =
// pure bf16 rounding) -> MFMA layout proven correct; this round recovers
// precision via x = hi + lo decomposition: A@B ~= Ah@Bh + Ah@Bl + Al@Bh.
// ---------------------------------------------------------------------------

#define DEVFN static __device__ __forceinline__

DEVFN float siluf(float x) { return x / (1.f + expf(-x)); }

DEVFN unsigned short f2bf(float x) {
    union { float f; unsigned u; } v; v.f = x;
    return (unsigned short)((v.u + 0x7FFFu + ((v.u >> 16) & 1u)) >> 16);
}
DEVFN float bf2f(unsigned short h) {
    union { unsigned u; float f; } v; v.u = ((unsigned)h) << 16;
    return v.f;
}

typedef __attribute__((ext_vector_type(8))) short bf16x8;
typedef __attribute__((ext_vector_type(4))) float f32x4;

// ------------- split-bf16 MFMA GEMM: C = act(A @ W^T + bias) (+res) --------
// A: [M,K] fp32 row-major (lda); W: [OUT,K] fp32 row-major; C: [M,OUT] fp32.
// Each fp32 staged as (hi, lo) bf16 pair; 3 MFMA products, fp32 accumulate.
// Tile 128x128, 4 waves (2x2 of 64x64), BK=32.
// LDS row pitch 40 shorts (80B): quarter-wave ds_read_b128 spreads over
// 8 bank-bases -> 2 lanes/bank = conflict-free (m136).
template <int ACT>
__launch_bounds__(256) __global__
void gemm_bf16(const float* __restrict__ A, int lda,
               const float* __restrict__ W,
               const float* __restrict__ bias,
               const float* __restrict__ res, int ldr,
               float* __restrict__ C, int ldc,
               int M, int K, int OUT)
{
    constexpr int LDP = 40;
    __shared__ short AsH[128 * LDP];
    __shared__ short AsL[128 * LDP];
    __shared__ short WsH[128 * LDP];
    __shared__ short WsL[128 * LDP];
    const int tid = threadIdx.x;
    const int bm = blockIdx.x * 128;
    const int bn = blockIdx.y * 128;
    const int w = tid >> 6, lane = tid & 63;
    const int wm = (w >> 1) * 64, wn = (w & 1) * 64;
    const int lr = lane & 15, lc = lane >> 4;

    f32x4 acc[4][4];
#pragma unroll
    for (int i = 0; i < 4; ++i)
#pragma unroll
        for (int j = 0; j < 4; ++j) acc[i][j] = (f32x4){0.f, 0.f, 0.f, 0.f};

    const int srow = tid & 127;         // staged row within tile
    const int scol0 = (tid >> 7) * 16;  // which 16-col half of the 32-col chunk

    for (int k0 = 0; k0 < K; k0 += 32) {
        // ---- stage A tile (rows bm+srow, cols k0+scol0..+15), fp32->hi/lo
        {
            int gm = bm + srow;
            const float* ap = A + (size_t)gm * lda + k0 + scol0;
            short sh[16], sl[16];
#pragma unroll
            for (int q = 0; q < 4; ++q) {
                int c = k0 + scol0 + q * 4;
                float4 vv = {0.f, 0.f, 0.f, 0.f};
                if (gm < M) {
                    if (c + 3 < K) {
                        vv = *reinterpret_cast<const float4*>(ap + q * 4);
                    } else {
                        if (c < K)     vv.x = ap[q * 4 + 0];
                        if (c + 1 < K) vv.y = ap[q * 4 + 1];
                        if (c + 2 < K) vv.z = ap[q * 4 + 2];
                        if (c + 3 < K) vv.w = ap[q * 4 + 3];
                    }
                }
                float e[4] = {vv.x, vv.y, vv.z, vv.w};
#pragma unroll
                for (int t = 0; t < 4; ++t) {
                    unsigned short hi = f2bf(e[t]);
                    sh[q * 4 + t] = (short)hi;
                    sl[q * 4 + t] = (short)f2bf(e[t] - bf2f(hi));
                }
            }
            *reinterpret_cast<bf16x8*>(&AsH[srow * LDP + scol0])     = *reinterpret_cast<bf16x8*>(&sh[0]);
            *reinterpret_cast<bf16x8*>(&AsH[srow * LDP + scol0 + 8]) = *reinterpret_cast<bf16x8*>(&sh[8]);
            *reinterpret_cast<bf16x8*>(&AsL[srow * LDP + scol0])     = *reinterpret_cast<bf16x8*>(&sl[0]);
            *reinterpret_cast<bf16x8*>(&AsL[srow * LDP + scol0 + 8]) = *reinterpret_cast<bf16x8*>(&sl[8]);
        }
        // ---- stage W tile (rows bn+srow of W[OUT,K]), fp32->hi/lo
        {
            int go = bn + srow;
            const float* wp = W + (size_t)go * K + k0 + scol0;
            short sh[16], sl[16];
#pragma unroll
            for (int q = 0; q < 4; ++q) {
                int c = k0 + scol0 + q * 4;
                float4 vv = {0.f, 0.f, 0.f, 0.f};
                if (go < OUT) {
                    if (c + 3 < K) {
                        vv = *reinterpret_cast<const float4*>(wp + q * 4);
                    } else {
                        if (c < K)     vv.x = wp[q * 4 + 0];
                        if (c + 1 < K) vv.y = wp[q * 4 + 1];
                        if (c + 2 < K) vv.z = wp[q * 4 + 2];
                        if (c + 3 < K) vv.w = wp[q * 4 + 3];
                    }
                }
                float e[4] = {vv.x, vv.y, vv.z, vv.w};
#pragma unroll
                for (int t = 0; t < 4; ++t) {
                    unsigned short hi = f2bf(e[t]);
                    sh[q * 4 + t] = (short)hi;
                    sl[q * 4 + t] = (short)f2bf(e[t] - bf2f(hi));
                }
            }
            *reinterpret_cast<bf16x8*>(&WsH[srow * LDP + scol0])     = *reinterpret_cast<bf16x8*>(&sh[0]);
            *reinterpret_cast<bf16x8*>(&WsH[srow * LDP + scol0 + 8]) = *reinterpret_cast<bf16x8*>(&sh[8]);
            *reinterpret_cast<bf16x8*>(&WsL[srow * LDP + scol0])     = *reinterpret_cast<bf16x8*>(&sl[0]);
            *reinterpret_cast<bf16x8*>(&WsL[srow * LDP + scol0 + 8]) = *reinterpret_cast<bf16x8*>(&sl[8]);
        }
        __syncthreads();

        // ---- fragments + 48 MFMA (hi*hi, hi*lo, lo*hi)
        bf16x8 afh[4], afl[4], bfh[4], bfl[4];
#pragma unroll
        for (int f = 0; f < 4; ++f) {
            afh[f] = *reinterpret_cast<const bf16x8*>(&AsH[(wm + f * 16 + lr) * LDP + lc * 8]);
            afl[f] = *reinterpret_cast<const bf16x8*>(&AsL[(wm + f * 16 + lr) * LDP + lc * 8]);
            bfh[f] = *reinterpret_cast<const bf16x8*>(&WsH[(wn + f * 16 + lr) * LDP + lc * 8]);
            bfl[f] = *reinterpret_cast<const bf16x8*>(&WsL[(wn + f * 16 + lr) * LDP + lc * 8]);
        }
#pragma unroll
        for (int i = 0; i < 4; ++i)
#pragma unroll
            for (int j = 0; j < 4; ++j) {
                acc[i][j] = __builtin_amdgcn_mfma_f32_16x16x32_bf16(afh[i], bfh[j], acc[i][j], 0, 0, 0);
                acc[i][j] = __builtin_amdgcn_mfma_f32_16x16x32_bf16(afh[i], bfl[j], acc[i][j], 0, 0, 0);
                acc[i][j] = __builtin_amdgcn_mfma_f32_16x16x32_bf16(afl[i], bfh[j], acc[i][j], 0, 0, 0);
            }
        __syncthreads();
    }

    // ---- epilogue: C/D layout col=lane&15, row=(lane>>4)*4+reg (m89)
#pragma unroll
    for (int i = 0; i < 4; ++i) {
#pragma unroll
        for (int j = 0; j < 4; ++j) {
            int col = bn + wn + j * 16 + lr;
            float bv = bias ? bias[col] : 0.f;
#pragma unroll
            for (int r = 0; r < 4; ++r) {
                int m = bm + wm + i * 16 + lc * 4 + r;
                if (m < M) {
                    float v = acc[i][j][r] + bv;
                    if (ACT == 1) v = siluf(v);
                    if (res) v += res[(size_t)m * ldr + col];
                    C[(size_t)m * ldc + col] = v;
                }
            }
        }
    }
}

// ------------------------- fp32 GEMM (head only) ---------------------------
template <int BM, int BN, int TM, int TN, int ACT>
__launch_bounds__(256) __global__
void gemm_nt(const float* __restrict__ A, int lda,
             const float* __restrict__ W,
             const float* __restrict__ bias,
             const float* __restrict__ res, int ldr,
             float* __restrict__ C, int ldc,
             int M, int K, int OUT)
{
    constexpr int BK = 16;
    __shared__ alignas(16) float As[BK][BM];
    __shared__ alignas(16) float Bs[BK][BN];
    const int tid = threadIdx.x;
    const int bm = blockIdx.x * BM;
    const int bn = blockIdx.y * BN;
    const int tr = (tid >> 4) * TM;
    const int tc = (tid & 15) * TN;

    float acc[TM][TN];
#pragma unroll
    for (int i = 0; i < TM; ++i)
#pragma unroll
        for (int j = 0; j < TN; ++j) acc[i][j] = 0.f;

    for (int k0 = 0; k0 < K; k0 += BK) {
#pragma unroll
        for (int it = 0; it < BM / 64; ++it) {
            int idx = tid + it * 256;
            int m = idx >> 2, kq = idx & 3;
            int gm = bm + m, gk = k0 + kq * 4;
            float t[4] = {0.f, 0.f, 0.f, 0.f};
            if (gm < M) {
#pragma unroll
                for (int j = 0; j < 4; ++j)
                    if (gk + j < K) t[j] = A[(size_t)gm * lda + gk + j];
            }
            As[kq * 4 + 0][m] = t[0];
            As[kq * 4 + 1][m] = t[1];
            As[kq * 4 + 2][m] = t[2];
            As[kq * 4 + 3][m] = t[3];
        }
#pragma unroll
        for (int it = 0; it < BN / 64; ++it) {
            int idx = tid + it * 256;
            int o = idx >> 2, kq = idx & 3;
            int go = bn + o, gk = k0 + kq * 4;
            float t[4] = {0.f, 0.f, 0.f, 0.f};
            if (go < OUT) {
#pragma unroll
                for (int j = 0; j < 4; ++j)
                    if (gk + j < K) t[j] = W[(size_t)go * K + gk + j];
            }
            Bs[kq * 4 + 0][o] = t[0];
            Bs[kq * 4 + 1][o] = t[1];
            Bs[kq * 4 + 2][o] = t[2];
            Bs[kq * 4 + 3][o] = t[3];
        }
        __syncthreads();
#pragma unroll
        for (int kk = 0; kk < BK; ++kk) {
            float a[TM], b[TN];
#pragma unroll
            for (int p = 0; p < TM; ++p) a[p] = As[kk][tr + p];
#pragma unroll
            for (int p = 0; p < TN; ++p) b[p] = Bs[kk][tc + p];
#pragma unroll
            for (int i = 0; i < TM; ++i)
#pragma unroll
                for (int j = 0; j < TN; ++j) acc[i][j] += a[i] * b[j];
        }
        __syncthreads();
    }

#pragma unroll
    for (int i = 0; i < TM; ++i) {
        int m = bm + tr + i;
        if (m >= M) continue;
#pragma unroll
        for (int j = 0; j < TN; ++j) {
            int o = bn + tc + j;
            if (o >= OUT) continue;
            float v = acc[i][j];
            if (bias) v += bias[o];
            if (ACT == 1) v = siluf(v);
            if (res) v += res[(size_t)m * ldr + o];
            C[(size_t)m * ldc + o] = v;
        }
    }
}

// ------------------------- small elementwise kernels ------------------------
__global__ void node_prep_k(const float* __restrict__ x, float* __restrict__ fx,
                            float* __restrict__ px, int n)
{
    int i = blockIdx.x * blockDim.x + threadIdx.x;
    if (i < n) {
        float v = x[i];
        fx[i] = floorf(v);
        px[i] = (v - truncf(v)) * 1000.f;
    }
}

__global__ void table_rbf_k(float* __restrict__ out, int T, float dmin, float step)
{
    int idx = blockIdx.x * blockDim.x + threadIdx.x;   // T*64 threads
    if (idx >= T * 64) return;
    int t = idx >> 6, j4 = (idx & 63) * 4;
    float dv = dmin + step * (float)t;
    float r[4];
#pragma unroll
    for (int j = 0; j < 4; ++j) {
        float c = -6.f + 6.f * (float)(j4 + j) * (1.f / 255.f);
        float u = dv - c;
        r[j] = expf(-42.5f * u * u);
    }
    float4 v = {r[0], r[1], r[2], r[3]};
    *reinterpret_cast<float4*>(out + (size_t)t * 256 + j4) = v;
}

__global__ void edge_prep_k(const float* __restrict__ ea, int* __restrict__ i0,
                            float* __restrict__ fr, int E, float dmin, float invstep, int T)
{
    int i = blockIdx.x * blockDim.x + threadIdx.x;
    if (i < E) {
        float a = ea[(size_t)i * 3], b = ea[(size_t)i * 3 + 1], c = ea[(size_t)i * 3 + 2];
        float d = -1.f / sqrtf(a * a + b * b + c * c);
        float u = (d - dmin) * invstep;
        u = fminf(fmaxf(u, 0.f), (float)(T - 1) - 1e-3f);
        int t0 = (int)u;
        i0[i] = t0;
        fr[i] = u - (float)t0;
    }
}

__global__ void ppe_prep_k(float* __restrict__ ppe, const float* __restrict__ h,
                           const float* __restrict__ pg, const float* __restrict__ pbeta,
                           float* __restrict__ bn, int n)
{
    int i = blockIdx.x * blockDim.x + threadIdx.x;
    if (i < n) {
        float adj = ppe[i] + h[i];
        ppe[i] = adj;
        int f = i & 255;
        bn[i] = adj * pg[f] + pbeta[f];
    }
}

__global__ void gate_k(const float* __restrict__ x1, const float* __restrict__ a2,
                       float* __restrict__ g, int n)
{
    int i = blockIdx.x * blockDim.x + threadIdx.x;
    if (i < n) {
        int m = i >> 8, f = i & 255;
        float x2 = a2[(size_t)m * 512 + 256 + f];
        float ge = 0.5f * x2 * (1.f + erff(x2 * 0.70710678118654752f));
        g[i] = x1[i] * ge;
    }
}

// ------------------------- edge sort by dst (counting sort) ----------------
__global__ void hist_k(const int* __restrict__ dst, int* __restrict__ deg, int E)
{
    int i = blockIdx.x * blockDim.x + threadIdx.x;
    if (i < E) atomicAdd(&deg[dst[i]], 1);
}

__global__ void scan_k(const int* __restrict__ deg, int* __restrict__ off, int n)
{
    __shared__ int buf[1024];
    __shared__ int carry;
    const int t = threadIdx.x;
    if (t == 0) carry = 0;
    __syncthreads();
    for (int base = 0; base < n; base += 1024) {
        int i = base + t;
        int v = (i < n) ? deg[i] : 0;
        buf[t] = v;
        __syncthreads();
        for (int s = 1; s < 1024; s <<= 1) {
            int add = (t >= s) ? buf[t - s] : 0;
            __syncthreads();
            buf[t] += add;
            __syncthreads();
        }
        if (i < n) off[i] = carry + buf[t] - v;
        __syncthreads();
        if (t == 0) carry += buf[1023];
        __syncthreads();
    }
    if (t == 0) off[n] = carry;
}

__global__ void copy_int_k(const int* __restrict__ a, int* __restrict__ b, int n)
{
    int i = blockIdx.x * blockDim.x + threadIdx.x;
    if (i < n) b[i] = a[i];
}

__global__ void scatter_k(const int* __restrict__ dst, int* __restrict__ cursor,
                          int* __restrict__ esort, int E)
{
    int i = blockIdx.x * blockDim.x + threadIdx.x;
    if (i < E) {
        int p = atomicAdd(&cursor[dst[i]], 1);
        esort[p] = i;
    }
}

// ------------------------- attention aggregate (wave per node) --------------
__launch_bounds__(256) __global__
void attn_agg_k(const float* __restrict__ q, const float* __restrict__ kx,
                const float* __restrict__ vx, const float* __restrict__ etab,
                const int* __restrict__ ei0, const float* __restrict__ efr,
                const int* __restrict__ src, const int* __restrict__ esort,
                const int* __restrict__ off, float* __restrict__ sbuf,
                float* __restrict__ hn, int Nn)
{
    int node = blockIdx.x * 4 + (threadIdx.x >> 6);
    if (node >= Nn) return;
    int lane = threadIdx.x & 63;
    int lo = off[node], hi = off[node + 1];
    if (lo >= hi) return;

    float4 qv = *reinterpret_cast<const float4*>(q + (size_t)node * 256 + lane * 4);

    float mx = -3.4e38f;
    for (int jj = lo; jj < hi; ++jj) {
        int eid = esort[jj];
        int sp = src[eid];
        int t0 = ei0[eid];
        float f = efr[eid];
        float4 kv = *reinterpret_cast<const float4*>(kx + (size_t)sp * 256 + lane * 4);
        float4 e0 = *reinterpret_cast<const float4*>(etab + (size_t)t0 * 256 + lane * 4);
        float4 e1 = *reinterpret_cast<const float4*>(etab + (size_t)(t0 + 1) * 256 + lane * 4);
        float ex0 = e0.x + f * (e1.x - e0.x);
        float ex1 = e0.y + f * (e1.y - e0.y);
        float ex2 = e0.z + f * (e1.z - e0.z);
        float ex3 = e0.w + f * (e1.w - e0.w);
        float p = qv.x * (kv.x + ex0) + qv.y * (kv.y + ex1) +
                  qv.z * (kv.z + ex2) + qv.w * (kv.w + ex3);
#pragma unroll
        for (int s = 32; s; s >>= 1) p += __shfl_xor(p, s, 64);
        if (lane == 0) sbuf[jj] = p;
        mx = fmaxf(mx, p);
    }
    float ax = 0.f, ay = 0.f, az = 0.f, aw = 0.f, den = 0.f;
    for (int jj = lo; jj < hi; ++jj) {
        int eid = esort[jj];
        int sp = src[eid];
        int t0 = ei0[eid];
        float f = efr[eid];
        float4 vv = *reinterpret_cast<const float4*>(vx + (size_t)sp * 256 + lane * 4);
        float4 e0 = *reinterpret_cast<const float4*>(etab + (size_t)t0 * 256 + lane * 4);
        float4 e1 = *reinterpret_cast<const float4*>(etab + (size_t)(t0 + 1) * 256 + lane * 4);
        float ex0 = e0.x + f * (e1.x - e0.x);
        float ex1 = e0.y + f * (e1.y - e0.y);
        float ex2 = e0.z + f * (e1.z - e0.z);
        float ex3 = e0.w + f * (e1.w - e0.w);
        float w = expf((sbuf[jj] - mx) * 0.0625f);
        den += w;
        ax += w * (vv.x + ex0);
        ay += w * (vv.y + ex1);
        az += w * (vv.z + ex2);
        aw += w * (vv.w + ex3);
    }
    float inv = 1.f / den;
    float4* o4 = reinterpret_cast<float4*>(hn + (size_t)node * 256 + lane * 4);
    float4 cur = *o4;
    cur.x += ax * inv; cur.y += ay * inv; cur.z += az * inv; cur.w += aw * inv;
    *o4 = cur;
}

// ------------------------- pooling / output ---------------------------------
__launch_bounds__(256) __global__
void pool_mean_k(const float* __restrict__ h, const int* __restrict__ batch,
                 float* __restrict__ tot, int Nn)
{
    int g = blockIdx.x;
    __shared__ int sl, sh;
    if (threadIdx.x == 0) {
        int lo = 0, hi = Nn;
        while (lo < hi) { int mid = (lo + hi) >> 1; if (batch[mid] < g) lo = mid + 1; else hi = mid; }
        sl = lo;
        lo = 0; hi = Nn;
        while (lo < hi) { int mid = (lo + hi) >> 1; if (batch[mid] < g + 1) lo = mid + 1; else hi = mid; }
        sh = lo;
    }
    __syncthreads();
    float acc = 0.f;
    for (int n = sl; n < sh; ++n) acc += h[(size_t)n * 256 + threadIdx.x];
    float c = (float)(sh - sl);
    if (c < 1.f) c = 1.f;
    tot[(size_t)g * 256 + threadIdx.x] = acc / c;
}

__launch_bounds__(256) __global__
void out_k(const float* __restrict__ crystal, const float* __restrict__ oW,
           const float* __restrict__ ob, const float* __restrict__ nosda,
           float* __restrict__ out, int Bn)
{
    int b = blockIdx.x;
    __shared__ float red[256];
    float p = crystal[(size_t)b * 256 + threadIdx.x] * oW[threadIdx.x];
    red[threadIdx.x] = p;
    __syncthreads();
    for (int s = 128; s; s >>= 1) {
        if (threadIdx.x < s) red[threadIdx.x] += red[threadIdx.x + s];
        __syncthreads();
    }
    if (threadIdx.x == 0) out[b] = (red[0] + ob[0]) / nosda[b];
}

// ---------------------------------------------------------------------------
extern "C" void kernel_launch(void* const* d_in, const int* in_sizes, int n_in,
                              void* d_out, int out_size, void* d_ws, size_t ws_size,
                              hipStream_t stream)
{
    const float* x     = (const float*)d_in[0];
    const int*   ei    = (const int*)d_in[1];
    const float* ea    = (const float*)d_in[2];
    const int*   batch = (const int*)d_in[3];
    const float* nosda = (const float*)d_in[4];
    const float* ae_W1 = (const float*)d_in[5];
    const float* ae_b1 = (const float*)d_in[6];
    const float* ae_W2 = (const float*)d_in[7];
    const float* ae_b2 = (const float*)d_in[8];
    const float* ee_W  = (const float*)d_in[9];
    const float* ee_b  = (const float*)d_in[10];
    const float* pe_W  = (const float*)d_in[11];
    const float* pe_b  = (const float*)d_in[12];
    const float* Wq    = (const float*)d_in[13];
    const float* bq    = (const float*)d_in[14];
    const float* Wk    = (const float*)d_in[15];
    const float* bk    = (const float*)d_in[16];
    const float* Wv    = (const float*)d_in[17];
    const float* bv    = (const float*)d_in[18];
    const float* We    = (const float*)d_in[19];
    const float* be    = (const float*)d_in[20];
    const float* Ws    = (const float*)d_in[21];
    const float* bs    = (const float*)d_in[22];
    const float* pW1   = (const float*)d_in[23];
    const float* pb1   = (const float*)d_in[24];
    const float* pW2   = (const float*)d_in[25];
    const float* pb2   = (const float*)d_in[26];
    const float* pW3   = (const float*)d_in[27];
    const float* pb3   = (const float*)d_in[28];
    const float* pg    = (const float*)d_in[29];
    const float* pbeta = (const float*)d_in[30];
    const float* fc_W  = (const float*)d_in[31];
    const float* fc_b  = (const float*)d_in[32];
    const float* out_W = (const float*)d_in[33];
    const float* out_b = (const float*)d_in[34];

    const int CG = 92, F = 256;
    const int N = in_sizes[0] / CG;
    const int E = in_sizes[1] / 2;
    const int B = in_sizes[4];
    const int T = 4096;
    const float DMIN = -8.f, DMAX = 0.f;
    const float STEP = (DMAX - DMIN) / (float)(T - 1);
    const int* src  = ei;
    const int* dstp = ei + E;

    // ---- workspace carve-up (~210 MB) -------------------------------------
    float* w = (float*)d_ws;
    auto take = [&](size_t n) { float* p = w; w += n; return p; };
    const size_t NF = (size_t)N * F;
    float* hb0  = take(NF);
    float* hb1  = take(NF);
    float* ppeb = take(NF);
    float* qb   = take(NF);
    float* kb   = take(NF);
    float* vb   = take(NF);
    float* a2b  = take(2 * NF);
    float* fx   = take((size_t)N * CG);
    float* px   = take((size_t)N * CG);
    float* rbft = take((size_t)T * F);
    float* eft  = take((size_t)T * F);
    float* etab = take((size_t)4 * T * F);
    float* efr  = take(E);
    float* sbuf = take(E);
    float* totb = take((size_t)B * F);
    float* cryb = take((size_t)B * F);
    int* ei0    = (int*)w; w += E;
    int* deg    = (int*)w; w += N;
    int* offb   = (int*)w; w += (N + 1);
    int* curb   = (int*)w; w += N;
    int* esort  = (int*)w; w += E;
    size_t need = (size_t)((char*)w - (char*)d_ws);
    if (need > ws_size) return;
    (void)n_in; (void)out_size;

    dim3 blk(256);
    auto g1 = [](int n) { return dim3((n + 255) / 256); };

    auto gbf = [&](const float* A, int lda, const float* Wt, const float* bias,
                   const float* res, int ldr, float* C, int ldc,
                   int M, int K, int OUT, int act) {
        dim3 grid((M + 127) / 128, (OUT + 127) / 128);
        if (act)
            gemm_bf16<1><<<grid, blk, 0, stream>>>(A, lda, Wt, bias, res, ldr, C, ldc, M, K, OUT);
        else
            gemm_bf16<0><<<grid, blk, 0, stream>>>(A, lda, Wt, bias, res, ldr, C, ldc, M, K, OUT);
    };

    // ---- prep + tables
    node_prep_k<<<g1(N * CG), blk, 0, stream>>>(x, fx, px, N * CG);
    edge_prep_k<<<g1(E), blk, 0, stream>>>(ea, ei0, efr, E, DMIN, 1.f / STEP, T);
    table_rbf_k<<<g1(T * 64), blk, 0, stream>>>(rbft, T, DMIN, STEP);

    gbf(rbft, F, ee_W, ee_b, nullptr, 0, eft, F, T, F, F, 1);       // ef table
    for (int i = 0; i < 4; ++i)
        gbf(eft, F, We + (size_t)i * F * F, be + (size_t)i * F, nullptr, 0,
            etab + (size_t)i * T * F, F, T, F, F, 0);               // e tables

    // ---- embeddings
    gbf(fx, CG, ae_W1, ae_b1, nullptr, 0, kb, F, N, CG, F, 1);
    gbf(kb, F, ae_W2, ae_b2, nullptr, 0, hb0, F, N, F, F, 0);
    gbf(px, CG, pe_W, pe_b, nullptr, 0, ppeb, F, N, CG, F, 0);

    // ---- counting-sort edges by dst
    hipMemsetAsync(deg, 0, (size_t)N * sizeof(int), stream);
    hist_k<<<g1(E), blk, 0, stream>>>(dstp, deg, E);
    scan_k<<<1, 1024, 0, stream>>>(deg, offb, N);
    copy_int_k<<<g1(N), blk, 0, stream>>>(offb, curb, N);
    scatter_k<<<g1(E), blk, 0, stream>>>(dstp, curb, esort, E);

    float* h  = hb0;
    float* hn = hb1;
    for (int i = 0; i < 4; ++i) {
        const float* Wq_i = Wq + (size_t)i * F * F; const float* bq_i = bq + (size_t)i * F;
        const float* Wk_i = Wk + (size_t)i * F * F; const float* bk_i = bk + (size_t)i * F;
        const float* Wv_i = Wv + (size_t)i * F * F; const float* bv_i = bv + (size_t)i * F;
        const float* Ws_i = Ws + (size_t)i * F * F; const float* bs_i = bs + (size_t)i * F;

        gbf(h, F, Wq_i, bq_i, nullptr, 0, qb, F, N, F, F, 0);
        gbf(h, F, Wk_i, bk_i, nullptr, 0, kb, F, N, F, F, 0);
        gbf(h, F, Wv_i, bv_i, nullptr, 0, vb, F, N, F, F, 0);
        gbf(h, F, Ws_i, bs_i, nullptr, 0, hn, F, N, F, F, 0);

        attn_agg_k<<<dim3((N + 3) / 4), blk, 0, stream>>>(
            qb, kb, vb, etab + (size_t)i * T * F, ei0, efr, src, esort, offb, sbuf, hn, N);
        { float* t = h; h = hn; hn = t; }

        if (i < 3) {
            const float* pW1_i = pW1 + (size_t)i * 2 * F * F; const float* pb1_i = pb1 + (size_t)i * 2 * F;
            const float* pW2_i = pW2 + (size_t)i * F * F;     const float* pb2_i = pb2 + (size_t)i * F;
            const float* pW3_i = pW3 + (size_t)i * F * F;     const float* pb3_i = pb3 + (size_t)i * F;

            ppe_prep_k<<<g1(N * F), blk, 0, stream>>>(ppeb, h, pg + (size_t)i * F, pbeta + (size_t)i * F, vb, N * F);
            gbf(vb, F, pW1_i, pb1_i, nullptr, 0, a2b, 2 * F, N, F, 2 * F, 0);
            gbf(a2b, 2 * F, pW2_i, pb2_i, nullptr, 0, qb, F, N, F, F, 0);
            gate_k<<<g1(N * F), blk, 0, stream>>>(qb, a2b, kb, N * F);
            gbf(kb, F, pW3_i, pb3_i, h, F, hn, F, N, F, F, 0);
            { float* t = h; h = hn; hn = t; }
        }
    }

    // ---- pooling + head (fp32)
    pool_mean_k<<<dim3(B), blk, 0, stream>>>(h, batch, totb, N);
    {
        dim3 grid((B + 63) / 64, (F + 63) / 64);
        gemm_nt<64, 64, 4, 4, 1><<<grid, blk, 0, stream>>>(totb, F, fc_W, fc_b, totb, F, cryb, F, B, F, F);
    }
    out_k<<<dim3(B), blk, 0, stream>>>(cryb, out_W, out_b, nosda, (float*)d_out, B);
}

// Round 8
// 1833.650 us; speedup vs baseline: 1.5250x; 1.2307x over previous
//
#include <hip/hip_runtime.h>
#include <cstdint>
#include <cstddef>

// ---------------------------------------------------------------------------
// Zeoformer forward. Split-bf16 (hi+lo, 3-product) MFMA GEMMs with
// PRE-SPLIT weights + fused q/k/v/skip GEMM (OUT=1024) + single-pass
// online-softmax attention. Tabulated edge embedding.
// N=20000, E=320000, B=64, F=256, CG=92, NL=4, NP=3.
// Round-7: identical compute, but workspace was 299MB > ws_size (~256MB);
// the fail-loud guard returned early -> zero output (absmax 17.25 = max|ref|).
// Fix: time-shared arena {qkvs} XOR {a2b,s2b,s3} XOR {fx,px,rbft,eft}
// -> ~194MB total. No algorithm changes vs round 7.
// ---------------------------------------------------------------------------

#define DEVFN static __device__ __forceinline__

DEVFN float siluf(float x) { return x / (1.f + expf(-x)); }

DEVFN unsigned short f2bf(float x) {
    union { float f; unsigned u; } v; v.f = x;
    return (unsigned short)((v.u + 0x7FFFu + ((v.u >> 16) & 1u)) >> 16);
}
DEVFN float bf2f(unsigned short h) {
    union { unsigned u; float f; } v; v.u = ((unsigned)h) << 16;
    return v.f;
}

typedef __attribute__((ext_vector_type(8))) short bf16x8;
typedef __attribute__((ext_vector_type(4))) float f32x4;

// ------------- split-bf16 MFMA GEMM, pre-split W planes --------------------
// A: [M,K] fp32 row-major (lda) -> split to hi/lo during staging.
// Whi/Wlo: [OUT,Kp] bf16 planes (Kp = K rounded up to 32, zero-padded).
// C: [M,OUT] fp32 (ldc). Tile 128x128, 4 waves, BK=32, 3 MFMA products.
// LDS pitch 40 shorts: quarter-wave ds_read_b128 -> 2 lanes/bank (free, m136).
template <int ACT>
__launch_bounds__(256) __global__
void gemm_sw(const float* __restrict__ A, int lda,
             const short* __restrict__ Whi, const short* __restrict__ Wlo, int Kp,
             const float* __restrict__ bias,
             const float* __restrict__ res, int ldr,
             float* __restrict__ C, int ldc,
             int M, int K, int OUT)
{
    constexpr int LDP = 40;
    __shared__ short AsH[128 * LDP];
    __shared__ short AsL[128 * LDP];
    __shared__ short WsH[128 * LDP];
    __shared__ short WsL[128 * LDP];
    const int tid = threadIdx.x;
    const int bm = blockIdx.x * 128;
    const int bn = blockIdx.y * 128;
    const int w = tid >> 6, lane = tid & 63;
    const int wm = (w >> 1) * 64, wn = (w & 1) * 64;
    const int lr = lane & 15, lc = lane >> 4;

    f32x4 acc[4][4];
#pragma unroll
    for (int i = 0; i < 4; ++i)
#pragma unroll
        for (int j = 0; j < 4; ++j) acc[i][j] = (f32x4){0.f, 0.f, 0.f, 0.f};

    const int srow = tid & 127;         // staged row within tile
    const int scol0 = (tid >> 7) * 16;  // 16-col half of the 32-col chunk

    for (int k0 = 0; k0 < K; k0 += 32) {
        // ---- stage A tile: fp32 -> hi/lo bf16 (the only conversion left)
        {
            int gm = bm + srow;
            const float* ap = A + (size_t)gm * lda + k0 + scol0;
            short sh[16], sl[16];
#pragma unroll
            for (int q = 0; q < 4; ++q) {
                int c = k0 + scol0 + q * 4;
                float4 vv = {0.f, 0.f, 0.f, 0.f};
                if (gm < M) {
                    if (c + 3 < K) {
                        vv = *reinterpret_cast<const float4*>(ap + q * 4);
                    } else {
                        if (c < K)     vv.x = ap[q * 4 + 0];
                        if (c + 1 < K) vv.y = ap[q * 4 + 1];
                        if (c + 2 < K) vv.z = ap[q * 4 + 2];
                        if (c + 3 < K) vv.w = ap[q * 4 + 3];
                    }
                }
                float e[4] = {vv.x, vv.y, vv.z, vv.w};
#pragma unroll
                for (int t = 0; t < 4; ++t) {
                    unsigned short hi = f2bf(e[t]);
                    sh[q * 4 + t] = (short)hi;
                    sl[q * 4 + t] = (short)f2bf(e[t] - bf2f(hi));
                }
            }
            *reinterpret_cast<bf16x8*>(&AsH[srow * LDP + scol0])     = *reinterpret_cast<bf16x8*>(&sh[0]);
            *reinterpret_cast<bf16x8*>(&AsH[srow * LDP + scol0 + 8]) = *reinterpret_cast<bf16x8*>(&sh[8]);
            *reinterpret_cast<bf16x8*>(&AsL[srow * LDP + scol0])     = *reinterpret_cast<bf16x8*>(&sl[0]);
            *reinterpret_cast<bf16x8*>(&AsL[srow * LDP + scol0 + 8]) = *reinterpret_cast<bf16x8*>(&sl[8]);
        }
        // ---- stage W tile: plain short8 copies from pre-split planes
        {
            int go = bn + srow;
            if (go < OUT) {
                const short* wh = Whi + (size_t)go * Kp + k0 + scol0;
                const short* wl = Wlo + (size_t)go * Kp + k0 + scol0;
                *reinterpret_cast<bf16x8*>(&WsH[srow * LDP + scol0])     = *reinterpret_cast<const bf16x8*>(wh);
                *reinterpret_cast<bf16x8*>(&WsH[srow * LDP + scol0 + 8]) = *reinterpret_cast<const bf16x8*>(wh + 8);
                *reinterpret_cast<bf16x8*>(&WsL[srow * LDP + scol0])     = *reinterpret_cast<const bf16x8*>(wl);
                *reinterpret_cast<bf16x8*>(&WsL[srow * LDP + scol0 + 8]) = *reinterpret_cast<const bf16x8*>(wl + 8);
            } else {
                bf16x8 z = {0, 0, 0, 0, 0, 0, 0, 0};
                *reinterpret_cast<bf16x8*>(&WsH[srow * LDP + scol0])     = z;
                *reinterpret_cast<bf16x8*>(&WsH[srow * LDP + scol0 + 8]) = z;
                *reinterpret_cast<bf16x8*>(&WsL[srow * LDP + scol0])     = z;
                *reinterpret_cast<bf16x8*>(&WsL[srow * LDP + scol0 + 8]) = z;
            }
        }
        __syncthreads();

        // ---- fragments + 48 MFMA (hi*hi, hi*lo, lo*hi)
        bf16x8 afh[4], afl[4], bfh[4], bfl[4];
#pragma unroll
        for (int f = 0; f < 4; ++f) {
            afh[f] = *reinterpret_cast<const bf16x8*>(&AsH[(wm + f * 16 + lr) * LDP + lc * 8]);
            afl[f] = *reinterpret_cast<const bf16x8*>(&AsL[(wm + f * 16 + lr) * LDP + lc * 8]);
            bfh[f] = *reinterpret_cast<const bf16x8*>(&WsH[(wn + f * 16 + lr) * LDP + lc * 8]);
            bfl[f] = *reinterpret_cast<const bf16x8*>(&WsL[(wn + f * 16 + lr) * LDP + lc * 8]);
        }
#pragma unroll
        for (int i = 0; i < 4; ++i)
#pragma unroll
            for (int j = 0; j < 4; ++j) {
                acc[i][j] = __builtin_amdgcn_mfma_f32_16x16x32_bf16(afh[i], bfh[j], acc[i][j], 0, 0, 0);
                acc[i][j] = __builtin_amdgcn_mfma_f32_16x16x32_bf16(afh[i], bfl[j], acc[i][j], 0, 0, 0);
                acc[i][j] = __builtin_amdgcn_mfma_f32_16x16x32_bf16(afl[i], bfh[j], acc[i][j], 0, 0, 0);
            }
        __syncthreads();
    }

    // ---- epilogue: C/D layout col=lane&15, row=(lane>>4)*4+reg (m89)
#pragma unroll
    for (int i = 0; i < 4; ++i) {
#pragma unroll
        for (int j = 0; j < 4; ++j) {
            int col = bn + wn + j * 16 + lr;
            if (col >= OUT) continue;
            float bv = bias ? bias[col] : 0.f;
#pragma unroll
            for (int r = 0; r < 4; ++r) {
                int m = bm + wm + i * 16 + lc * 4 + r;
                if (m < M) {
                    float v = acc[i][j][r] + bv;
                    if (ACT == 1) v = siluf(v);
                    if (res) v += res[(size_t)m * ldr + col];
                    C[(size_t)m * ldc + col] = v;
                }
            }
        }
    }
}

// ------------------------- fp32 GEMM (head only) ---------------------------
template <int BM, int BN, int TM, int TN, int ACT>
__launch_bounds__(256) __global__
void gemm_nt(const float* __restrict__ A, int lda,
             const float* __restrict__ W,
             const float* __restrict__ bias,
             const float* __restrict__ res, int ldr,
             float* __restrict__ C, int ldc,
             int M, int K, int OUT)
{
    constexpr int BK = 16;
    __shared__ alignas(16) float As[BK][BM];
    __shared__ alignas(16) float Bs[BK][BN];
    const int tid = threadIdx.x;
    const int bm = blockIdx.x * BM;
    const int bn = blockIdx.y * BN;
    const int tr = (tid >> 4) * TM;
    const int tc = (tid & 15) * TN;

    float acc[TM][TN];
#pragma unroll
    for (int i = 0; i < TM; ++i)
#pragma unroll
        for (int j = 0; j < TN; ++j) acc[i][j] = 0.f;

    for (int k0 = 0; k0 < K; k0 += BK) {
#pragma unroll
        for (int it = 0; it < BM / 64; ++it) {
            int idx = tid + it * 256;
            int m = idx >> 2, kq = idx & 3;
            int gm = bm + m, gk = k0 + kq * 4;
            float t[4] = {0.f, 0.f, 0.f, 0.f};
            if (gm < M) {
#pragma unroll
                for (int j = 0; j < 4; ++j)
                    if (gk + j < K) t[j] = A[(size_t)gm * lda + gk + j];
            }
            As[kq * 4 + 0][m] = t[0];
            As[kq * 4 + 1][m] = t[1];
            As[kq * 4 + 2][m] = t[2];
            As[kq * 4 + 3][m] = t[3];
        }
#pragma unroll
        for (int it = 0; it < BN / 64; ++it) {
            int idx = tid + it * 256;
            int o = idx >> 2, kq = idx & 3;
            int go = bn + o, gk = k0 + kq * 4;
            float t[4] = {0.f, 0.f, 0.f, 0.f};
            if (go < OUT) {
#pragma unroll
                for (int j = 0; j < 4; ++j)
                    if (gk + j < K) t[j] = W[(size_t)go * K + gk + j];
            }
            Bs[kq * 4 + 0][o] = t[0];
            Bs[kq * 4 + 1][o] = t[1];
            Bs[kq * 4 + 2][o] = t[2];
            Bs[kq * 4 + 3][o] = t[3];
        }
        __syncthreads();
#pragma unroll
        for (int kk = 0; kk < BK; ++kk) {
            float a[TM], b[TN];
#pragma unroll
            for (int p = 0; p < TM; ++p) a[p] = As[kk][tr + p];
#pragma unroll
            for (int p = 0; p < TN; ++p) b[p] = Bs[kk][tc + p];
#pragma unroll
            for (int i = 0; i < TM; ++i)
#pragma unroll
                for (int j = 0; j < TN; ++j) acc[i][j] += a[i] * b[j];
        }
        __syncthreads();
    }

#pragma unroll
    for (int i = 0; i < TM; ++i) {
        int m = bm + tr + i;
        if (m >= M) continue;
#pragma unroll
        for (int j = 0; j < TN; ++j) {
            int o = bn + tc + j;
            if (o >= OUT) continue;
            float v = acc[i][j];
            if (bias) v += bias[o];
            if (ACT == 1) v = siluf(v);
            if (res) v += res[(size_t)m * ldr + o];
            C[(size_t)m * ldc + o] = v;
        }
    }
}

// ------------------------- weight prep kernels -----------------------------
__global__ void split_w_k(const float* __restrict__ src, short* __restrict__ dhi,
                          short* __restrict__ dlo, int OUT, int K, int Kp)
{
    int idx = blockIdx.x * blockDim.x + threadIdx.x;
    if (idx >= OUT * Kp) return;
    int row = idx / Kp, col = idx - row * Kp;
    float v = (col < K) ? src[(size_t)row * K + col] : 0.f;
    unsigned short hi = f2bf(v);
    dhi[idx] = (short)hi;
    dlo[idx] = (short)f2bf(v - bf2f(hi));
}

// Stack Wq/Wk/Wv/Ws ([NL,256,256] each) -> [NL][1024][256] split planes.
__global__ void stack_qkvs_w_k(const float* __restrict__ Wq, const float* __restrict__ Wk,
                               const float* __restrict__ Wv, const float* __restrict__ Ws,
                               short* __restrict__ dhi, short* __restrict__ dlo, int total)
{
    int idx = blockIdx.x * blockDim.x + threadIdx.x;
    if (idx >= total) return;
    int col = idx & 255;
    int row = (idx >> 8) & 1023;
    int layer = idx >> 18;
    int s2 = row >> 8;
    const float* s = (s2 == 0) ? Wq : ((s2 == 1) ? Wk : ((s2 == 2) ? Wv : Ws));
    float v = s[(size_t)layer * 65536 + (size_t)(row & 255) * 256 + col];
    unsigned short hi = f2bf(v);
    dhi[idx] = (short)hi;
    dlo[idx] = (short)f2bf(v - bf2f(hi));
}

__global__ void stack_qkvs_b_k(const float* __restrict__ bq, const float* __restrict__ bk,
                               const float* __restrict__ bv, const float* __restrict__ bs,
                               float* __restrict__ dst, int total)
{
    int idx = blockIdx.x * blockDim.x + threadIdx.x;
    if (idx >= total) return;
    int r = idx & 1023, layer = idx >> 10;
    int s2 = r >> 8;
    const float* s = (s2 == 0) ? bq : ((s2 == 1) ? bk : ((s2 == 2) ? bv : bs));
    dst[idx] = s[layer * 256 + (r & 255)];
}

// ------------------------- small elementwise kernels ------------------------
__global__ void node_prep_k(const float* __restrict__ x, float* __restrict__ fx,
                            float* __restrict__ px, int n)
{
    int i = blockIdx.x * blockDim.x + threadIdx.x;
    if (i < n) {
        float v = x[i];
        fx[i] = floorf(v);
        px[i] = (v - truncf(v)) * 1000.f;
    }
}

__global__ void table_rbf_k(float* __restrict__ out, int T, float dmin, float step)
{
    int idx = blockIdx.x * blockDim.x + threadIdx.x;   // T*64 threads
    if (idx >= T * 64) return;
    int t = idx >> 6, j4 = (idx & 63) * 4;
    float dv = dmin + step * (float)t;
    float r[4];
#pragma unroll
    for (int j = 0; j < 4; ++j) {
        float c = -6.f + 6.f * (float)(j4 + j) * (1.f / 255.f);
        float u = dv - c;
        r[j] = expf(-42.5f * u * u);
    }
    float4 v = {r[0], r[1], r[2], r[3]};
    *reinterpret_cast<float4*>(out + (size_t)t * 256 + j4) = v;
}

__global__ void edge_prep_k(const float* __restrict__ ea, int* __restrict__ i0,
                            float* __restrict__ fr, int E, float dmin, float invstep, int T)
{
    int i = blockIdx.x * blockDim.x + threadIdx.x;
    if (i < E) {
        float a = ea[(size_t)i * 3], b = ea[(size_t)i * 3 + 1], c = ea[(size_t)i * 3 + 2];
        float d = -1.f / sqrtf(a * a + b * b + c * c);
        float u = (d - dmin) * invstep;
        u = fminf(fmaxf(u, 0.f), (float)(T - 1) - 1e-3f);
        int t0 = (int)u;
        i0[i] = t0;
        fr[i] = u - (float)t0;
    }
}

__global__ void ppe_prep_k(float* __restrict__ ppe, const float* __restrict__ h,
                           const float* __restrict__ pg, const float* __restrict__ pbeta,
                           float* __restrict__ bn, int n)
{
    int i = blockIdx.x * blockDim.x + threadIdx.x;
    if (i < n) {
        float adj = ppe[i] + h[i];
        ppe[i] = adj;
        int f = i & 255;
        bn[i] = adj * pg[f] + pbeta[f];
    }
}

__global__ void gate_k(const float* __restrict__ x1, const float* __restrict__ a2,
                       float* __restrict__ g, int n)
{
    int i = blockIdx.x * blockDim.x + threadIdx.x;
    if (i < n) {
        int m = i >> 8, f = i & 255;
        float x2 = a2[(size_t)m * 512 + 256 + f];
        float ge = 0.5f * x2 * (1.f + erff(x2 * 0.70710678118654752f));
        g[i] = x1[i] * ge;
    }
}

// ------------------------- edge sort by dst (counting sort) ----------------
__global__ void hist_k(const int* __restrict__ dst, int* __restrict__ deg, int E)
{
    int i = blockIdx.x * blockDim.x + threadIdx.x;
    if (i < E) atomicAdd(&deg[dst[i]], 1);
}

__global__ void scan_k(const int* __restrict__ deg, int* __restrict__ off, int n)
{
    __shared__ int buf[1024];
    __shared__ int carry;
    const int t = threadIdx.x;
    if (t == 0) carry = 0;
    __syncthreads();
    for (int base = 0; base < n; base += 1024) {
        int i = base + t;
        int v = (i < n) ? deg[i] : 0;
        buf[t] = v;
        __syncthreads();
        for (int s = 1; s < 1024; s <<= 1) {
            int add = (t >= s) ? buf[t - s] : 0;
            __syncthreads();
            buf[t] += add;
            __syncthreads();
        }
        if (i < n) off[i] = carry + buf[t] - v;
        __syncthreads();
        if (t == 0) carry += buf[1023];
        __syncthreads();
    }
    if (t == 0) off[n] = carry;
}

__global__ void copy_int_k(const int* __restrict__ a, int* __restrict__ b, int n)
{
    int i = blockIdx.x * blockDim.x + threadIdx.x;
    if (i < n) b[i] = a[i];
}

__global__ void scatter_k(const int* __restrict__ dst, int* __restrict__ cursor,
                          int* __restrict__ esort, int E)
{
    int i = blockIdx.x * blockDim.x + threadIdx.x;
    if (i < E) {
        int p = atomicAdd(&cursor[dst[i]], 1);
        esort[p] = i;
    }
}

// ---------------- single-pass online-softmax attention ---------------------
// qkvs: [N,1024] = q|k|v|skip. Per node (wave): one edge loop, online
// max/denominator rescale (exact), hn[node] = skip + agg.
__launch_bounds__(256) __global__
void attn_fused_k(const float* __restrict__ qkvs, const float* __restrict__ etab,
                  const int* __restrict__ ei0, const float* __restrict__ efr,
                  const int* __restrict__ src, const int* __restrict__ esort,
                  const int* __restrict__ off, float* __restrict__ hn, int Nn)
{
    int node = blockIdx.x * 4 + (threadIdx.x >> 6);
    if (node >= Nn) return;
    int lane = threadIdx.x & 63;
    int lo = off[node], hi = off[node + 1];

    const float* qrow = qkvs + (size_t)node * 1024;
    float4 qv = *reinterpret_cast<const float4*>(qrow + lane * 4);
    float4 sk = *reinterpret_cast<const float4*>(qrow + 768 + lane * 4);

    float m = -3.4e38f, den = 0.f;
    float ax = 0.f, ay = 0.f, az = 0.f, aw = 0.f;

    for (int jj = lo; jj < hi; ++jj) {
        int eid = esort[jj];
        int sp = src[eid];
        int t0 = ei0[eid];
        float f = efr[eid];
        const float* srow = qkvs + (size_t)sp * 1024;
        float4 kv = *reinterpret_cast<const float4*>(srow + 256 + lane * 4);
        float4 e0 = *reinterpret_cast<const float4*>(etab + (size_t)t0 * 256 + lane * 4);
        float4 e1 = *reinterpret_cast<const float4*>(etab + (size_t)(t0 + 1) * 256 + lane * 4);
        float ex0 = e0.x + f * (e1.x - e0.x);
        float ex1 = e0.y + f * (e1.y - e0.y);
        float ex2 = e0.z + f * (e1.z - e0.z);
        float ex3 = e0.w + f * (e1.w - e0.w);
        float p = qv.x * (kv.x + ex0) + qv.y * (kv.y + ex1) +
                  qv.z * (kv.z + ex2) + qv.w * (kv.w + ex3);
#pragma unroll
        for (int s = 32; s; s >>= 1) p += __shfl_xor(p, s, 64);
        p *= 0.0625f;                                   // /sqrt(F)=16 exactly
        float4 vv = *reinterpret_cast<const float4*>(srow + 512 + lane * 4);
        float vx0 = vv.x + ex0, vx1 = vv.y + ex1, vx2 = vv.z + ex2, vx3 = vv.w + ex3;
        if (p > m) {                                    // wave-uniform branch
            float sc = expf(m - p);                     // first iter: exp(-inf)=0
            den = den * sc + 1.f;
            ax = ax * sc + vx0;
            ay = ay * sc + vx1;
            az = az * sc + vx2;
            aw = aw * sc + vx3;
            m = p;
        } else {
            float wgt = expf(p - m);
            den += wgt;
            ax += wgt * vx0;
            ay += wgt * vx1;
            az += wgt * vx2;
            aw += wgt * vx3;
        }
    }
    float inv = (hi > lo) ? 1.f / den : 0.f;
    float4 o = {sk.x + ax * inv, sk.y + ay * inv, sk.z + az * inv, sk.w + aw * inv};
    *reinterpret_cast<float4*>(hn + (size_t)node * 256 + lane * 4) = o;
}

// ------------------------- pooling / output ---------------------------------
__launch_bounds__(256) __global__
void pool_mean_k(const float* __restrict__ h, const int* __restrict__ batch,
                 float* __restrict__ tot, int Nn)
{
    int g = blockIdx.x;
    __shared__ int sl, sh;
    if (threadIdx.x == 0) {
        int lo = 0, hi = Nn;
        while (lo < hi) { int mid = (lo + hi) >> 1; if (batch[mid] < g) lo = mid + 1; else hi = mid; }
        sl = lo;
        lo = 0; hi = Nn;
        while (lo < hi) { int mid = (lo + hi) >> 1; if (batch[mid] < g + 1) lo = mid + 1; else hi = mid; }
        sh = lo;
    }
    __syncthreads();
    float acc = 0.f;
    for (int n = sl; n < sh; ++n) acc += h[(size_t)n * 256 + threadIdx.x];
    float c = (float)(sh - sl);
    if (c < 1.f) c = 1.f;
    tot[(size_t)g * 256 + threadIdx.x] = acc / c;
}

__launch_bounds__(256) __global__
void out_k(const float* __restrict__ crystal, const float* __restrict__ oW,
           const float* __restrict__ ob, const float* __restrict__ nosda,
           float* __restrict__ out, int Bn)
{
    int b = blockIdx.x;
    __shared__ float red[256];
    float p = crystal[(size_t)b * 256 + threadIdx.x] * oW[threadIdx.x];
    red[threadIdx.x] = p;
    __syncthreads();
    for (int s = 128; s; s >>= 1) {
        if (threadIdx.x < s) red[threadIdx.x] += red[threadIdx.x + s];
        __syncthreads();
    }
    if (threadIdx.x == 0) out[b] = (red[0] + ob[0]) / nosda[b];
}

// ---------------------------------------------------------------------------
extern "C" void kernel_launch(void* const* d_in, const int* in_sizes, int n_in,
                              void* d_out, int out_size, void* d_ws, size_t ws_size,
                              hipStream_t stream)
{
    const float* x     = (const float*)d_in[0];
    const int*   ei    = (const int*)d_in[1];
    const float* ea    = (const float*)d_in[2];
    const int*   batch = (const int*)d_in[3];
    const float* nosda = (const float*)d_in[4];
    const float* ae_W1 = (const float*)d_in[5];
    const float* ae_b1 = (const float*)d_in[6];
    const float* ae_W2 = (const float*)d_in[7];
    const float* ae_b2 = (const float*)d_in[8];
    const float* ee_W  = (const float*)d_in[9];
    const float* ee_b  = (const float*)d_in[10];
    const float* pe_W  = (const float*)d_in[11];
    const float* pe_b  = (const float*)d_in[12];
    const float* Wq    = (const float*)d_in[13];
    const float* bq    = (const float*)d_in[14];
    const float* Wk    = (const float*)d_in[15];
    const float* bk    = (const float*)d_in[16];
    const float* Wv    = (const float*)d_in[17];
    const float* bv    = (const float*)d_in[18];
    const float* We    = (const float*)d_in[19];
    const float* be    = (const float*)d_in[20];
    const float* Ws    = (const float*)d_in[21];
    const float* bs    = (const float*)d_in[22];
    const float* pW1   = (const float*)d_in[23];
    const float* pb1   = (const float*)d_in[24];
    const float* pW2   = (const float*)d_in[25];
    const float* pb2   = (const float*)d_in[26];
    const float* pW3   = (const float*)d_in[27];
    const float* pb3   = (const float*)d_in[28];
    const float* pg    = (const float*)d_in[29];
    const float* pbeta = (const float*)d_in[30];
    const float* fc_W  = (const float*)d_in[31];
    const float* fc_b  = (const float*)d_in[32];
    const float* out_W = (const float*)d_in[33];
    const float* out_b = (const float*)d_in[34];

    const int CG = 92, F = 256;
    const int N = in_sizes[0] / CG;
    const int E = in_sizes[1] / 2;
    const int B = in_sizes[4];
    const int T = 4096;
    const float DMIN = -8.f, DMAX = 0.f;
    const float STEP = (DMAX - DMIN) / (float)(T - 1);
    const int* src  = ei;
    const int* dstp = ei + E;

    // ---- workspace carve-up (~194 MB, ws_size budget ~256 MB) --------------
    // Arena (N*1024 floats) is time-shared by three disjoint-lifetime tenants:
    //   T1 (pre-loop):  fx, px, rbft, eft        (5.8M floats)
    //   T2 (attn):      qkvs                      (20.48M)
    //   T3 (ppe):       a2b, s2b, s3              (20.48M)
    // qkvs is dead after attn_fused_k; ppe scratch dead before next qkvs GEMM;
    // T1 dead before layer 0.
    float* w = (float*)d_ws;
    auto take = [&](size_t n) { float* p = w; w += n; return p; };
    auto takeS = [&](size_t nshorts) { short* p = (short*)w; w += (nshorts + 1) / 2; return p; };
    const size_t NF = (size_t)N * F;
    const size_t NCG = (size_t)N * CG;
    float* hb0  = take(NF);
    float* hb1  = take(NF);
    float* ppeb = take(NF);
    float* s1   = take(NF);               // embed scratch + ppe bn scratch
    float* arena = take((size_t)N * 1024);
    float* qkvs = arena;                  // T2
    float* a2b  = arena;                  // T3 [N,512]
    float* s2b  = arena + 2 * NF;         // T3
    float* s3   = arena + 3 * NF;         // T3
    float* fx   = arena;                  // T1
    float* px   = arena + NCG;            // T1
    float* rbft = arena + 2 * NCG;        // T1 [T,256]
    float* eft  = arena + 2 * NCG + (size_t)T * F;   // T1 [T,256]
    float* etab = take((size_t)4 * T * F);
    float* efr  = take(E);
    float* totb = take((size_t)B * F);
    float* cryb = take((size_t)B * F);
    float* bstk = take(4 * 1024);
    // split-bf16 weight planes
    short* qwHi = takeS((size_t)4 * 1024 * 256);
    short* qwLo = takeS((size_t)4 * 1024 * 256);
    short* eeHi = takeS((size_t)256 * 256);
    short* eeLo = takeS((size_t)256 * 256);
    short* weHi = takeS((size_t)4 * 256 * 256);
    short* weLo = takeS((size_t)4 * 256 * 256);
    short* a1Hi = takeS((size_t)256 * 96);
    short* a1Lo = takeS((size_t)256 * 96);
    short* a2Hi = takeS((size_t)256 * 256);
    short* a2Lo = takeS((size_t)256 * 256);
    short* peHi = takeS((size_t)256 * 96);
    short* peLo = takeS((size_t)256 * 96);
    short* p1Hi = takeS((size_t)3 * 512 * 256);
    short* p1Lo = takeS((size_t)3 * 512 * 256);
    short* p2Hi = takeS((size_t)3 * 256 * 256);
    short* p2Lo = takeS((size_t)3 * 256 * 256);
    short* p3Hi = takeS((size_t)3 * 256 * 256);
    short* p3Lo = takeS((size_t)3 * 256 * 256);
    int* ei0    = (int*)w; w += E;
    int* deg    = (int*)w; w += N;
    int* offb   = (int*)w; w += (N + 1);
    int* curb   = (int*)w; w += N;
    int* esort  = (int*)w; w += E;
    size_t need = (size_t)((char*)w - (char*)d_ws);
    if (need > ws_size) return;               // fail loud, not a fault
    (void)n_in; (void)out_size;

    dim3 blk(256);
    auto g1 = [](int n) { return dim3((n + 255) / 256); };

    auto gsw = [&](const float* A, int lda, const short* Whi, const short* Wlo, int Kp,
                   const float* bias, const float* res, int ldr, float* C, int ldc,
                   int M, int K, int OUT, int act) {
        dim3 grid((M + 127) / 128, (OUT + 127) / 128);
        if (act)
            gemm_sw<1><<<grid, blk, 0, stream>>>(A, lda, Whi, Wlo, Kp, bias, res, ldr, C, ldc, M, K, OUT);
        else
            gemm_sw<0><<<grid, blk, 0, stream>>>(A, lda, Whi, Wlo, Kp, bias, res, ldr, C, ldc, M, K, OUT);
    };

    // ---- prep + weight splitting
    node_prep_k<<<g1(N * CG), blk, 0, stream>>>(x, fx, px, N * CG);
    edge_prep_k<<<g1(E), blk, 0, stream>>>(ea, ei0, efr, E, DMIN, 1.f / STEP, T);
    table_rbf_k<<<g1(T * 64), blk, 0, stream>>>(rbft, T, DMIN, STEP);

    stack_qkvs_w_k<<<g1(4 * 1024 * 256), blk, 0, stream>>>(Wq, Wk, Wv, Ws, qwHi, qwLo, 4 * 1024 * 256);
    stack_qkvs_b_k<<<g1(4 * 1024), blk, 0, stream>>>(bq, bk, bv, bs, bstk, 4 * 1024);
    split_w_k<<<g1(256 * 256), blk, 0, stream>>>(ee_W, eeHi, eeLo, 256, 256, 256);
    split_w_k<<<g1(4 * 256 * 256), blk, 0, stream>>>(We, weHi, weLo, 1024, 256, 256);
    split_w_k<<<g1(256 * 96), blk, 0, stream>>>(ae_W1, a1Hi, a1Lo, 256, 92, 96);
    split_w_k<<<g1(256 * 256), blk, 0, stream>>>(ae_W2, a2Hi, a2Lo, 256, 256, 256);
    split_w_k<<<g1(256 * 96), blk, 0, stream>>>(pe_W, peHi, peLo, 256, 92, 96);
    split_w_k<<<g1(3 * 512 * 256), blk, 0, stream>>>(pW1, p1Hi, p1Lo, 1536, 256, 256);
    split_w_k<<<g1(3 * 256 * 256), blk, 0, stream>>>(pW2, p2Hi, p2Lo, 768, 256, 256);
    split_w_k<<<g1(3 * 256 * 256), blk, 0, stream>>>(pW3, p3Hi, p3Lo, 768, 256, 256);

    // ---- tables: ef = silu(rbf@eeW), e_i = ef@We_i   (T1 arena tenants)
    gsw(rbft, F, eeHi, eeLo, 256, ee_b, nullptr, 0, eft, F, T, F, F, 1);
    for (int i = 0; i < 4; ++i)
        gsw(eft, F, weHi + (size_t)i * 65536, weLo + (size_t)i * 65536, 256,
            be + (size_t)i * F, nullptr, 0, etab + (size_t)i * T * F, F, T, F, F, 0);

    // ---- embeddings (fx/px still live in T1)
    gsw(fx, CG, a1Hi, a1Lo, 96, ae_b1, nullptr, 0, s1, F, N, CG, F, 1);
    gsw(s1, F, a2Hi, a2Lo, 256, ae_b2, nullptr, 0, hb0, F, N, F, F, 0);
    gsw(px, CG, peHi, peLo, 96, pe_b, nullptr, 0, ppeb, F, N, CG, F, 0);

    // ---- counting-sort edges by dst
    hipMemsetAsync(deg, 0, (size_t)N * sizeof(int), stream);
    hist_k<<<g1(E), blk, 0, stream>>>(dstp, deg, E);
    scan_k<<<1, 1024, 0, stream>>>(deg, offb, N);
    copy_int_k<<<g1(N), blk, 0, stream>>>(offb, curb, N);
    scatter_k<<<g1(E), blk, 0, stream>>>(dstp, curb, esort, E);

    float* h  = hb0;
    float* hn = hb1;
    for (int i = 0; i < 4; ++i) {
        // fused q|k|v|skip GEMM: [N,256] @ [1024,256]^T -> [N,1024]  (T2)
        gsw(h, F, qwHi + (size_t)i * 1024 * 256, qwLo + (size_t)i * 1024 * 256, 256,
            bstk + (size_t)i * 1024, nullptr, 0, qkvs, 1024, N, F, 1024, 0);

        attn_fused_k<<<dim3((N + 3) / 4), blk, 0, stream>>>(
            qkvs, etab + (size_t)i * T * F, ei0, efr, src, esort, offb, hn, N);
        { float* t = h; h = hn; hn = t; }

        if (i < 3) {                                     // ppe phase (T3)
            ppe_prep_k<<<g1(N * F), blk, 0, stream>>>(ppeb, h, pg + (size_t)i * F, pbeta + (size_t)i * F, s1, N * F);
            gsw(s1, F, p1Hi + (size_t)i * 512 * 256, p1Lo + (size_t)i * 512 * 256, 256,
                pb1 + (size_t)i * 2 * F, nullptr, 0, a2b, 2 * F, N, F, 2 * F, 0);
            gsw(a2b, 2 * F, p2Hi + (size_t)i * 65536, p2Lo + (size_t)i * 65536, 256,
                pb2 + (size_t)i * F, nullptr, 0, s2b, F, N, F, F, 0);
            gate_k<<<g1(N * F), blk, 0, stream>>>(s2b, a2b, s3, N * F);
            gsw(s3, F, p3Hi + (size_t)i * 65536, p3Lo + (size_t)i * 65536, 256,
                pb3 + (size_t)i * F, h, F, hn, F, N, F, F, 0);
            { float* t = h; h = hn; hn = t; }
        }
    }

    // ---- pooling + head (fp32)
    pool_mean_k<<<dim3(B), blk, 0, stream>>>(h, batch, totb, N);
    {
        dim3 grid((B + 63) / 64, (F + 63) / 64);
        gemm_nt<64, 64, 4, 4, 1><<<grid, blk, 0, stream>>>(totb, F, fc_W, fc_b, totb, F, cryb, F, B, F, F);
    }
    out_k<<<dim3(B), blk, 0, stream>>>(cryb, out_W, out_b, nosda, (float*)d_out, B);
}